// Round 3
// baseline (517.675 us; speedup 1.0000x reference)
//
#include <hip/hip_runtime.h>
#include <hip/hip_bf16.h>

#define NN 8192
#define KK 32

typedef __attribute__((ext_vector_type(8))) short short8v;   // 8 bf16 in 4 VGPRs
typedef __attribute__((ext_vector_type(4))) float float4v;   // MFMA 16x16 acc

__device__ __forceinline__ float wave_reduce_sum(float v) {
    #pragma unroll
    for (int off = 32; off > 0; off >>= 1) v += __shfl_down(v, off);
    return v;
}
__device__ __forceinline__ float wave_reduce_max(float v) {
    #pragma unroll
    for (int off = 32; off > 0; off >>= 1) v = fmaxf(v, __shfl_down(v, off));
    return v;
}
__device__ __forceinline__ unsigned short f2bf(float x) {  // RNE fp32->bf16
    unsigned int u = __float_as_uint(x);
    return (unsigned short)((u + 0x7fffu + ((u >> 16) & 1u)) >> 16);
}
__device__ __forceinline__ float bf2f(unsigned short h) {
    return __uint_as_float(((unsigned int)h) << 16);
}

// ---------- K0: column softmax stats of C (N x K), one block per column l ----------
__global__ void kc_colstats(const float* __restrict__ C, float* __restrict__ mC,
                            float* __restrict__ sC) {
    const int l = blockIdx.x;
    const int t = threadIdx.x;  // 256
    __shared__ float wmax[4], wsum[4];

    float m = -INFINITY;
    for (int u = 0; u < NN / 256; ++u)
        m = fmaxf(m, C[(size_t)(u * 256 + t) * KK + l]);
    m = wave_reduce_max(m);
    if ((t & 63) == 0) wmax[t >> 6] = m;
    __syncthreads();
    const float mm = fmaxf(fmaxf(wmax[0], wmax[1]), fmaxf(wmax[2], wmax[3]));

    float s = 0.f;
    for (int u = 0; u < NN / 256; ++u)
        s += __expf(C[(size_t)(u * 256 + t) * KK + l] - mm);
    s = wave_reduce_sum(s);
    if ((t & 63) == 0) wsum[t >> 6] = s;
    __syncthreads();
    if (t == 0) {
        mC[l] = mm;
        sC[l] = wsum[0] + wsum[1] + wsum[2] + wsum[3];
    }
}

// ---------- K1: column softmax of X (K x N) -> Xs ----------
__global__ void kx_softmax(const float* __restrict__ X, float* __restrict__ Xs) {
    const int n = blockIdx.x * 256 + threadIdx.x;
    float e[KK];
    float m = -INFINITY;
    #pragma unroll
    for (int k = 0; k < KK; ++k) {
        e[k] = X[(size_t)k * NN + n];
        m = fmaxf(m, e[k]);
    }
    float s = 0.f;
    #pragma unroll
    for (int k = 0; k < KK; ++k) {
        e[k] = __expf(e[k] - m);
        s += e[k];
    }
    const float r = 1.f / s;
    #pragma unroll
    for (int k = 0; k < KK; ++k) Xs[(size_t)k * NN + n] = e[k] * r;
}

// ---------- K2: E = Xs @ softmax(C) ----------
__global__ void ke_E(const float* __restrict__ Xs, const float* __restrict__ C,
                     const float* __restrict__ mC, const float* __restrict__ sC,
                     float* __restrict__ E) {
    __shared__ float xsl[KK * 33];
    __shared__ float cql[32 * 33];
    __shared__ float mCl[KK], rsCl[KK];
    const int tid = threadIdx.x;     // 1024
    if (tid < KK) { mCl[tid] = mC[tid]; rsCl[tid] = 1.f / sC[tid]; }
    const int k = tid & 31, l = tid >> 5;
    const int sk = tid >> 5, sn = tid & 31;
    const int nb0 = blockIdx.x * (NN / 64);
    float acc = 0.f;
    for (int b = 0; b < 4; ++b) {
        const int nb = nb0 + b * 32;
        __syncthreads();
        xsl[sk * 33 + sn] = Xs[(size_t)sk * NN + nb + sn];
        const float cv = C[(size_t)nb * KK + tid];
        cql[(tid >> 5) * 33 + (tid & 31)] =
            __expf(cv - mCl[tid & 31]) * rsCl[tid & 31];
        __syncthreads();
        #pragma unroll
        for (int n = 0; n < 32; ++n)
            acc = fmaf(xsl[k * 33 + n], cql[n * 33 + l], acc);
    }
    atomicAdd(&E[k * KK + l], acc);
}

// ---------- K3: M = E^T E ----------
__global__ void km_M(const float* __restrict__ E, float* __restrict__ M) {
    __shared__ float el[KK * 33];
    const int tid = threadIdx.x;   // 1024
    el[(tid >> 5) * 33 + (tid & 31)] = E[tid];
    __syncthreads();
    const int l1 = tid & 31, l2 = tid >> 5;
    float acc = 0.f;
    #pragma unroll
    for (int kk = 0; kk < KK; ++kk)
        acc = fmaf(el[kk * 33 + l1], el[kk * 33 + l2], acc);
    M[tid] = acc;
}

// ---------- K4: per-node prep ----------
__global__ void kp_prep(const float* __restrict__ X, const float* __restrict__ beta,
                        const float* __restrict__ a_ptr, const float* __restrict__ Mm,
                        float* __restrict__ Xt, float* __restrict__ f,
                        unsigned short* __restrict__ Xh, unsigned short* __restrict__ Xl,
                        unsigned short* __restrict__ Wh, unsigned short* __restrict__ Wl,
                        unsigned short* __restrict__ Bh, unsigned short* __restrict__ Bl,
                        double* __restrict__ acc) {
    __shared__ float Ml[KK * KK];
    const int tid = threadIdx.x;  // 256
    #pragma unroll
    for (int u = 0; u < 4; ++u) Ml[tid + 256 * u] = Mm[tid + 256 * u];
    __syncthreads();
    const int n = blockIdx.x * 256 + tid;
    float x[KK], v[KK];
    #pragma unroll
    for (int k = 0; k < KK; ++k) x[k] = X[(size_t)k * NN + n];
    const float a = a_ptr[0];
    const float two_a = 2.f * a;
    #pragma unroll
    for (int l = 0; l < KK; ++l) {
        float s = 0.f;
        #pragma unroll
        for (int k = 0; k < KK; ++k) s = fmaf(Ml[l * KK + k], x[k], s);
        v[l] = two_a * s;                     // w = 2a M x
    }
    float q2 = 0.f;                           // = 2a x^T M x
    #pragma unroll
    for (int l = 0; l < KK; ++l) q2 = fmaf(x[l], v[l], q2);
    const float b = beta[n];
    const float fn = b - 0.5f * q2;           // f = beta - a x^T M x
    f[n] = fn;

    union PK { unsigned short u[8]; short8v s; };
    PK xh, xl, wh, wl;
    #pragma unroll
    for (int g = 0; g < 4; ++g) {
        #pragma unroll
        for (int e = 0; e < 8; ++e) {
            const int k = g * 8 + e;
            const float xv = x[k];
            Xt[(size_t)n * KK + k] = xv;
            const unsigned short h = f2bf(xv);
            xh.u[e] = h;
            xl.u[e] = f2bf(xv - bf2f(h));
            const float wv = v[k];
            const unsigned short hw = f2bf(wv);
            const unsigned short lw = f2bf(wv - bf2f(hw));
            wh.u[e] = hw;
            wl.u[e] = lw;
            Bh[(size_t)k * NN + n] = hw;      // transposed B panel for A-GEMM
            Bl[(size_t)k * NN + n] = lw;
        }
        *(short8v*)&Xh[(size_t)n * KK + g * 8] = xh.s;
        *(short8v*)&Xl[(size_t)n * KK + g * 8] = xl.s;
        *(short8v*)&Wh[(size_t)n * KK + g * 8] = wh.s;
        *(short8v*)&Wl[(size_t)n * KK + g * 8] = wl.s;
    }
    // B extra columns: col32 = 1.0 (rowsum), col33 = f (colsum-f term), 34..47 = 0
    Bh[(size_t)32 * NN + n] = 0x3F80; Bl[(size_t)32 * NN + n] = 0;
    const unsigned short hf = f2bf(fn);
    Bh[(size_t)33 * NN + n] = hf;
    Bl[(size_t)33 * NN + n] = f2bf(fn - bf2f(hf));
    #pragma unroll
    for (int k = 34; k < 48; ++k) {
        Bh[(size_t)k * NN + n] = 0;
        Bl[(size_t)k * NN + n] = 0;
    }
    // diagonal softplus: theta_ii = 2*beta_i exactly
    const float th = 2.f * b;
    float sp = fmaxf(th, 0.f) + __logf(1.f + __expf(-fabsf(th)));
    sp = wave_reduce_sum(sp);
    if ((tid & 63) == 0) atomicAdd(&acc[2], (double)sp);
}

// ---------- K5: fat kernel ----------
#define GEMM_BLOCKS 1024
#define GEMM_WAVES  (GEMM_BLOCKS * 4)
#define SP_BLOCKS   2048
#define FAT_BLOCKS  (GEMM_BLOCKS + SP_BLOCKS)

__global__ __launch_bounds__(256) void k_fat(
    const float* __restrict__ A, const float* __restrict__ f,
    const unsigned short* __restrict__ Xh, const unsigned short* __restrict__ Xl,
    const unsigned short* __restrict__ Wh, const unsigned short* __restrict__ Wl,
    const unsigned short* __restrict__ Bh, const unsigned short* __restrict__ Bl,
    float* __restrict__ Ppart, float* __restrict__ Ssc) {
    const int tid  = threadIdx.x;
    const int lane = tid & 63;
    const int l15  = lane & 15;
    const int klo  = (lane >> 4) << 3;
    const int wid  = blockIdx.x * 4 + (tid >> 6);

    if (blockIdx.x < GEMM_BLOCKS) {
        const int ibase = (wid >> 3) << 4;     // 512 i-tiles of 16 rows
        const int chunk = wid & 7;             // 8 j-chunks of 1024
        float4v c0 = {0.f, 0.f, 0.f, 0.f}, c1 = c0, c2 = c0;
        const float* arow = &A[(size_t)(ibase + l15) * NN];
        #pragma unroll 2
        for (int s = 0; s < 32; ++s) {
            const int j0 = (chunk << 10) + (s << 5) + klo;
            const float4 a0 = *(const float4*)&arow[j0];
            const float4 a1 = *(const float4*)&arow[j0 + 4];
            union { unsigned short u[8]; short8v s8; } af;
            af.u[0] = f2bf(a0.x); af.u[1] = f2bf(a0.y);
            af.u[2] = f2bf(a0.z); af.u[3] = f2bf(a0.w);
            af.u[4] = f2bf(a1.x); af.u[5] = f2bf(a1.y);
            af.u[6] = f2bf(a1.z); af.u[7] = f2bf(a1.w);
            const size_t bo = (size_t)l15 * NN + j0;
            short8v b;
            b = *(const short8v*)&Bh[bo];
            c0 = __builtin_amdgcn_mfma_f32_16x16x32_bf16(af.s8, b, c0, 0, 0, 0);
            b = *(const short8v*)&Bl[bo];
            c0 = __builtin_amdgcn_mfma_f32_16x16x32_bf16(af.s8, b, c0, 0, 0, 0);
            b = *(const short8v*)&Bh[bo + (size_t)16 * NN];
            c1 = __builtin_amdgcn_mfma_f32_16x16x32_bf16(af.s8, b, c1, 0, 0, 0);
            b = *(const short8v*)&Bl[bo + (size_t)16 * NN];
            c1 = __builtin_amdgcn_mfma_f32_16x16x32_bf16(af.s8, b, c1, 0, 0, 0);
            b = *(const short8v*)&Bh[bo + (size_t)32 * NN];
            c2 = __builtin_amdgcn_mfma_f32_16x16x32_bf16(af.s8, b, c2, 0, 0, 0);
            b = *(const short8v*)&Bl[bo + (size_t)32 * NN];
            c2 = __builtin_amdgcn_mfma_f32_16x16x32_bf16(af.s8, b, c2, 0, 0, 0);
        }
        // D layout: col = lane&15, row = (lane>>4)*4 + r
        const size_t pb = ((size_t)chunk * NN + ibase + ((lane >> 4) << 2)) * 48 + l15;
        #pragma unroll
        for (int r = 0; r < 4; ++r) {
            Ppart[pb + (size_t)r * 48]      = c0[r];
            Ppart[pb + (size_t)r * 48 + 16] = c1[r];
            Ppart[pb + (size_t)r * 48 + 32] = c2[r];
        }
    } else {
        const int t = wid - GEMM_WAVES;        // 0..8191
        const int ibase = (t >> 4) << 4;       // 512 i-tiles
        const int jc = (t & 15) << 9;          // 16 j-chunks of 512
        const short8v xh = *(const short8v*)&Xh[(size_t)(ibase + l15) * KK + klo];
        const short8v xl = *(const short8v*)&Xl[(size_t)(ibase + l15) * KK + klo];
        float fr[4];
        #pragma unroll
        for (int r = 0; r < 4; ++r) fr[r] = f[ibase + ((lane >> 4) << 2) + r];
        float accS = 0.f;
        for (int jt = 0; jt < 32; ++jt) {
            const int jb = jc + (jt << 4);
            const size_t wo = (size_t)(jb + l15) * KK + klo;
            const short8v wh = *(const short8v*)&Wh[wo];
            const short8v wl = *(const short8v*)&Wl[wo];
            const float fj = f[jb + l15];
            float4v d = {0.f, 0.f, 0.f, 0.f};
            d = __builtin_amdgcn_mfma_f32_16x16x32_bf16(xl, wh, d, 0, 0, 0);
            d = __builtin_amdgcn_mfma_f32_16x16x32_bf16(xh, wl, d, 0, 0, 0);
            d = __builtin_amdgcn_mfma_f32_16x16x32_bf16(xh, wh, d, 0, 0, 0);
            #pragma unroll
            for (int r = 0; r < 4; ++r) {
                const float th = fr[r] + fj + d[r];
                accS += fmaxf(th, 0.f) + __logf(1.f + __expf(-fabsf(th)));
            }
        }
        accS = wave_reduce_sum(accS);
        if (lane == 0) Ssc[t] = accS;
    }
}

// ---------- K6: reduce P partials + softplus scratch ----------
__global__ __launch_bounds__(256) void kr_reduce(
    const float* __restrict__ Ppart, const float* __restrict__ Xt,
    const float* __restrict__ f, const float* __restrict__ Ssc,
    double* __restrict__ acc) {
    const int i = blockIdx.x * 256 + threadIdx.x;  // 8192 threads
    float ps[48];
    #pragma unroll
    for (int q = 0; q < 48; ++q) ps[q] = 0.f;
    for (int c = 0; c < 8; ++c) {
        const float* pp = &Ppart[((size_t)c * NN + i) * 48];
        #pragma unroll
        for (int q = 0; q < 48; ++q) ps[q] += pp[q];
    }
    const float* xt = &Xt[(size_t)i * KK];
    float s = 0.f;
    #pragma unroll
    for (int k = 0; k < KK; ++k) s = fmaf(xt[k], ps[k], s);
    s += f[i] * ps[32] + ps[33];
    const float sA = wave_reduce_sum(s);
    const float sS = wave_reduce_sum(Ssc[i]);
    if ((threadIdx.x & 63) == 0) {
        atomicAdd(&acc[0], (double)sA);
        atomicAdd(&acc[1], (double)sS);
    }
}

// ---------- K7: finalize ----------
__global__ void kf_final(const double* __restrict__ acc, float* __restrict__ out) {
    out[0] = (float)(0.5 * (acc[0] - (acc[1] - acc[2])));
}

extern "C" void kernel_launch(void* const* d_in, const int* in_sizes, int n_in,
                              void* d_out, int out_size, void* d_ws, size_t ws_size,
                              hipStream_t stream) {
    const float* Ain    = (const float*)d_in[0];  // (N, N)
    const float* betain = (const float*)d_in[1];  // (N,)
    const float* ain    = (const float*)d_in[2];  // (1,)
    const float* Xin    = (const float*)d_in[3];  // (K, N)
    const float* Cin    = (const float*)d_in[4];  // (N, K)
    float* out = (float*)d_out;

    char* ws = (char*)d_ws;
    float*          E   = (float*)(ws + 0);                  // 4 KB
    double*         acc = (double*)(ws + 4096);              // 3 doubles
    float*          mC  = (float*)(ws + 4160);
    float*          sC  = (float*)(ws + 4288);
    float*          M   = (float*)(ws + 4608);               // 4 KB
    float*          f   = (float*)(ws + 8704);               // 32 KB
    float*          Xt  = (float*)(ws + 65536);              // 1 MB
    unsigned short* Xh  = (unsigned short*)(ws + 1114112);   // 512 KB
    unsigned short* Xl  = (unsigned short*)(ws + 1638400);   // 512 KB
    unsigned short* Wh  = (unsigned short*)(ws + 2162688);   // 512 KB
    unsigned short* Wl  = (unsigned short*)(ws + 2686976);   // 512 KB
    unsigned short* Bh  = (unsigned short*)(ws + 3211264);   // 768 KB
    unsigned short* Bl  = (unsigned short*)(ws + 3997696);   // 768 KB
    float*          Pp  = (float*)(ws + 4784128);            // 12 MB
    float*          Ssc = (float*)(ws + 17367040);           // 32 KB
    float*          Xs  = (float*)(ws + 17399808);           // 1 MB
    // total ~18.4 MB << ws_size

    hipMemsetAsync(ws, 0, 4128, stream);  // zero E + 3 double accs

    kc_colstats<<<KK, 256, 0, stream>>>(Cin, mC, sC);
    kx_softmax<<<NN / 256, 256, 0, stream>>>(Xin, Xs);
    ke_E<<<64, 1024, 0, stream>>>(Xs, Cin, mC, sC, E);
    km_M<<<1, 1024, 0, stream>>>(E, M);
    kp_prep<<<NN / 256, 256, 0, stream>>>(Xin, betain, ain, M, Xt, f,
                                          Xh, Xl, Wh, Wl, Bh, Bl, acc);
    k_fat<<<FAT_BLOCKS, 256, 0, stream>>>(Ain, f, Xh, Xl, Wh, Wl, Bh, Bl, Pp, Ssc);
    kr_reduce<<<NN / 256, 256, 0, stream>>>(Pp, Xt, f, Ssc, acc);
    kf_final<<<1, 1, 0, stream>>>(acc, out);
}

// Round 5
// 444.233 us; speedup vs baseline: 1.1653x; 1.1653x over previous
//
#include <hip/hip_runtime.h>
#include <hip/hip_bf16.h>

#define NN 8192
#define KK 32

typedef __attribute__((ext_vector_type(8))) short short8v;   // 8 bf16 in 4 VGPRs
typedef __attribute__((ext_vector_type(4))) float float4v;   // MFMA 16x16 acc

__device__ __forceinline__ float wave_reduce_sum(float v) {
    #pragma unroll
    for (int off = 32; off > 0; off >>= 1) v += __shfl_down(v, off);
    return v;
}
__device__ __forceinline__ float wave_reduce_max(float v) {
    #pragma unroll
    for (int off = 32; off > 0; off >>= 1) v = fmaxf(v, __shfl_down(v, off));
    return v;
}
__device__ __forceinline__ unsigned short f2bf(float x) {  // RNE fp32->bf16
    unsigned int u = __float_as_uint(x);
    return (unsigned short)((u + 0x7fffu + ((u >> 16) & 1u)) >> 16);
}
__device__ __forceinline__ float bf2f(unsigned short h) {
    return __uint_as_float(((unsigned int)h) << 16);
}

// ---------- K0: column softmax stats of C (N x K), one block per column l ----------
__global__ void kc_colstats(const float* __restrict__ C, float* __restrict__ mC,
                            float* __restrict__ sC) {
    const int l = blockIdx.x;
    const int t = threadIdx.x;  // 256
    __shared__ float wmax[4], wsum[4];

    float m = -INFINITY;
    for (int u = 0; u < NN / 256; ++u)
        m = fmaxf(m, C[(size_t)(u * 256 + t) * KK + l]);
    m = wave_reduce_max(m);
    if ((t & 63) == 0) wmax[t >> 6] = m;
    __syncthreads();
    const float mm = fmaxf(fmaxf(wmax[0], wmax[1]), fmaxf(wmax[2], wmax[3]));

    float s = 0.f;
    for (int u = 0; u < NN / 256; ++u)
        s += __expf(C[(size_t)(u * 256 + t) * KK + l] - mm);
    s = wave_reduce_sum(s);
    if ((t & 63) == 0) wsum[t >> 6] = s;
    __syncthreads();
    if (t == 0) {
        mC[l] = mm;
        sC[l] = wsum[0] + wsum[1] + wsum[2] + wsum[3];
    }
}

// ---------- K1: column softmax of X (K x N) -> Xs ----------
__global__ void kx_softmax(const float* __restrict__ X, float* __restrict__ Xs) {
    const int n = blockIdx.x * 256 + threadIdx.x;
    float e[KK];
    float m = -INFINITY;
    #pragma unroll
    for (int k = 0; k < KK; ++k) {
        e[k] = X[(size_t)k * NN + n];
        m = fmaxf(m, e[k]);
    }
    float s = 0.f;
    #pragma unroll
    for (int k = 0; k < KK; ++k) {
        e[k] = __expf(e[k] - m);
        s += e[k];
    }
    const float r = 1.f / s;
    #pragma unroll
    for (int k = 0; k < KK; ++k) Xs[(size_t)k * NN + n] = e[k] * r;
}

// ---------- K2: E = Xs @ softmax(C) ----------
__global__ void ke_E(const float* __restrict__ Xs, const float* __restrict__ C,
                     const float* __restrict__ mC, const float* __restrict__ sC,
                     float* __restrict__ E) {
    __shared__ float xsl[KK * 33];
    __shared__ float cql[32 * 33];
    __shared__ float mCl[KK], rsCl[KK];
    const int tid = threadIdx.x;     // 1024
    if (tid < KK) { mCl[tid] = mC[tid]; rsCl[tid] = 1.f / sC[tid]; }
    const int k = tid & 31, l = tid >> 5;
    const int sk = tid >> 5, sn = tid & 31;
    const int nb0 = blockIdx.x * (NN / 64);
    float acc = 0.f;
    for (int b = 0; b < 4; ++b) {
        const int nb = nb0 + b * 32;
        __syncthreads();
        xsl[sk * 33 + sn] = Xs[(size_t)sk * NN + nb + sn];
        const float cv = C[(size_t)nb * KK + tid];
        cql[(tid >> 5) * 33 + (tid & 31)] =
            __expf(cv - mCl[tid & 31]) * rsCl[tid & 31];
        __syncthreads();
        #pragma unroll
        for (int n = 0; n < 32; ++n)
            acc = fmaf(xsl[k * 33 + n], cql[n * 33 + l], acc);
    }
    atomicAdd(&E[k * KK + l], acc);
}

// ---------- K3: M = E^T E ----------
__global__ void km_M(const float* __restrict__ E, float* __restrict__ M) {
    __shared__ float el[KK * 33];
    const int tid = threadIdx.x;   // 1024
    el[(tid >> 5) * 33 + (tid & 31)] = E[tid];
    __syncthreads();
    const int l1 = tid & 31, l2 = tid >> 5;
    float acc = 0.f;
    #pragma unroll
    for (int kk = 0; kk < KK; ++kk)
        acc = fmaf(el[kk * 33 + l1], el[kk * 33 + l2], acc);
    M[tid] = acc;
}

// ---------- K4: per-node prep: f, bf16 hi/lo splits of x and w=2aMx, diag sp ----------
__global__ void kp_prep(const float* __restrict__ X, const float* __restrict__ beta,
                        const float* __restrict__ a_ptr, const float* __restrict__ Mm,
                        float* __restrict__ f,
                        unsigned short* __restrict__ Xh, unsigned short* __restrict__ Xl,
                        unsigned short* __restrict__ Wh, unsigned short* __restrict__ Wl,
                        double* __restrict__ acc) {
    __shared__ float Ml[KK * KK];
    const int tid = threadIdx.x;  // 256
    #pragma unroll
    for (int u = 0; u < 4; ++u) Ml[tid + 256 * u] = Mm[tid + 256 * u];
    __syncthreads();
    const int n = blockIdx.x * 256 + tid;
    float x[KK], v[KK];
    #pragma unroll
    for (int k = 0; k < KK; ++k) x[k] = X[(size_t)k * NN + n];
    const float a = a_ptr[0];
    const float two_a = 2.f * a;
    #pragma unroll
    for (int l = 0; l < KK; ++l) {
        float s = 0.f;
        #pragma unroll
        for (int k = 0; k < KK; ++k) s = fmaf(Ml[l * KK + k], x[k], s);
        v[l] = two_a * s;                     // w = 2a M x
    }
    float q2 = 0.f;                           // = 2a x^T M x
    #pragma unroll
    for (int l = 0; l < KK; ++l) q2 = fmaf(x[l], v[l], q2);
    const float b = beta[n];
    const float fn = b - 0.5f * q2;           // f = beta - a x^T M x
    f[n] = fn;

    union PK { unsigned short u[8]; short8v s; };
    PK xh, xl, wh, wl;
    #pragma unroll
    for (int g = 0; g < 4; ++g) {
        #pragma unroll
        for (int e = 0; e < 8; ++e) {
            const int k = g * 8 + e;
            const float xv = x[k];
            const unsigned short h = f2bf(xv);
            xh.u[e] = h;
            xl.u[e] = f2bf(xv - bf2f(h));
            const float wv = v[k];
            const unsigned short hw = f2bf(wv);
            wh.u[e] = hw;
            wl.u[e] = f2bf(wv - bf2f(hw));
        }
        *(short8v*)&Xh[(size_t)n * KK + g * 8] = xh.s;
        *(short8v*)&Xl[(size_t)n * KK + g * 8] = xl.s;
        *(short8v*)&Wh[(size_t)n * KK + g * 8] = wh.s;
        *(short8v*)&Wl[(size_t)n * KK + g * 8] = wl.s;
    }
    // diagonal softplus: theta_ii = 2*beta_i exactly (z_ii = 0)
    const float th = 2.f * b;
    float sp = fmaxf(th, 0.f) + __logf(1.f + __expf(-fabsf(th)));
    sp = wave_reduce_sum(sp);
    if ((tid & 63) == 0) atomicAdd(&acc[2], (double)sp);
}

// ---------- K5: unified pair kernel: accA and accS in one A-stream pass ----------
// 8192 waves (2048 blocks x 4): wave = (i-tile of 16 rows) x (j-chunk of 512)
__global__ __launch_bounds__(256) void k_pair(
    const float* __restrict__ A, const float* __restrict__ f,
    const unsigned short* __restrict__ Xh, const unsigned short* __restrict__ Xl,
    const unsigned short* __restrict__ Wh, const unsigned short* __restrict__ Wl,
    float* __restrict__ part) {
    const int tid  = threadIdx.x;
    const int lane = tid & 63;
    const int l15  = lane & 15;
    const int klo  = (lane >> 4) << 3;
    const int r0   = (lane >> 4) << 2;
    const int wid  = blockIdx.x * 4 + (tid >> 6);
    const int ibase = (wid >> 4) << 4;   // 512 i-tiles; block's 4 waves share it
    const int jc    = (wid & 15) << 9;   // 16 j-chunks of 512

    const short8v xh = *(const short8v*)&Xh[(size_t)(ibase + l15) * KK + klo];
    const short8v xl = *(const short8v*)&Xl[(size_t)(ibase + l15) * KK + klo];
    float fr[4];
    #pragma unroll
    for (int r = 0; r < 4; ++r) fr[r] = f[ibase + r0 + r];

    float accA = 0.f, accS = 0.f;
    #pragma unroll 2
    for (int jt = 0; jt < 32; ++jt) {
        const int jb = jc + (jt << 4);
        // A tile: 16x16 f32, D-layout aligned (row = r0+r, col = l15)
        float av[4];
        #pragma unroll
        for (int r = 0; r < 4; ++r)
            av[r] = A[(size_t)(ibase + r0 + r) * NN + jb + l15];
        const size_t wo = (size_t)(jb + l15) * KK + klo;
        const short8v wh = *(const short8v*)&Wh[wo];
        const short8v wl = *(const short8v*)&Wl[wo];
        const float fj = f[jb + l15];
        float4v d = {0.f, 0.f, 0.f, 0.f};
        d = __builtin_amdgcn_mfma_f32_16x16x32_bf16(xl, wh, d, 0, 0, 0);
        d = __builtin_amdgcn_mfma_f32_16x16x32_bf16(xh, wl, d, 0, 0, 0);
        d = __builtin_amdgcn_mfma_f32_16x16x32_bf16(xh, wh, d, 0, 0, 0);
        #pragma unroll
        for (int r = 0; r < 4; ++r) {
            const float th = fr[r] + fj + d[r];
            accA = fmaf(th, av[r], accA);
            accS += fmaxf(th, 0.f) + __logf(1.f + __expf(-fabsf(th)));
        }
    }

    accA = wave_reduce_sum(accA);
    accS = wave_reduce_sum(accS);
    __shared__ float rA[4], rS[4];
    if (lane == 0) { rA[tid >> 6] = accA; rS[tid >> 6] = accS; }
    __syncthreads();
    if (tid == 0) {
        part[blockIdx.x * 2]     = rA[0] + rA[1] + rA[2] + rA[3];
        part[blockIdx.x * 2 + 1] = rS[0] + rS[1] + rS[2] + rS[3];
    }
}

// ---------- K6: final deterministic reduction of 2048 block partials ----------
__global__ __launch_bounds__(1024) void kz_final(const float* __restrict__ part,
                                                 const double* __restrict__ acc,
                                                 float* __restrict__ out) {
    const int t = threadIdx.x;  // 1024 threads, 16 waves
    double dA = (double)part[2 * t]     + (double)part[2 * (t + 1024)];
    double dS = (double)part[2 * t + 1] + (double)part[2 * (t + 1024) + 1];
    #pragma unroll
    for (int off = 32; off > 0; off >>= 1) {
        dA += __shfl_down(dA, off);
        dS += __shfl_down(dS, off);
    }
    __shared__ double sA[16], sS[16];
    if ((t & 63) == 0) { sA[t >> 6] = dA; sS[t >> 6] = dS; }
    __syncthreads();
    if (t == 0) {
        double a = 0.0, s = 0.0;
        #pragma unroll
        for (int u = 0; u < 16; ++u) { a += sA[u]; s += sS[u]; }
        out[0] = (float)(0.5 * (a - (s - acc[2])));
    }
}

extern "C" void kernel_launch(void* const* d_in, const int* in_sizes, int n_in,
                              void* d_out, int out_size, void* d_ws, size_t ws_size,
                              hipStream_t stream) {
    const float* Ain    = (const float*)d_in[0];  // (N, N)
    const float* betain = (const float*)d_in[1];  // (N,)
    const float* ain    = (const float*)d_in[2];  // (1,)
    const float* Xin    = (const float*)d_in[3];  // (K, N)
    const float* Cin    = (const float*)d_in[4];  // (N, K)
    float* out = (float*)d_out;

    char* ws = (char*)d_ws;
    float*          E    = (float*)(ws + 0);                 // 4 KB
    double*         acc  = (double*)(ws + 4096);             // 3 doubles (acc[2] = diag sp)
    float*          mC   = (float*)(ws + 4160);
    float*          sC   = (float*)(ws + 4288);
    float*          M    = (float*)(ws + 4608);              // 4 KB
    float*          f    = (float*)(ws + 8704);              // 32 KB
    float*          part = (float*)(ws + 49152);             // 16 KB (2048 x float2)
    unsigned short* Xh   = (unsigned short*)(ws + 65536);    // 512 KB
    unsigned short* Xl   = (unsigned short*)(ws + 589824);   // 512 KB
    unsigned short* Wh   = (unsigned short*)(ws + 1114112);  // 512 KB
    unsigned short* Wl   = (unsigned short*)(ws + 1638400);  // 512 KB
    float*          Xs   = (float*)(ws + 2162688);           // 1 MB
    // total ~3.2 MB

    hipMemsetAsync(ws, 0, 4128, stream);  // zero E + 3 double accs

    kc_colstats<<<KK, 256, 0, stream>>>(Cin, mC, sC);
    kx_softmax<<<NN / 256, 256, 0, stream>>>(Xin, Xs);
    ke_E<<<64, 1024, 0, stream>>>(Xs, Cin, mC, sC, E);
    km_M<<<1, 1024, 0, stream>>>(E, M);
    kp_prep<<<NN / 256, 256, 0, stream>>>(Xin, betain, ain, M, f, Xh, Xl, Wh, Wl, acc);
    k_pair<<<2048, 256, 0, stream>>>(Ain, f, Xh, Xl, Wh, Wl, part);
    kz_final<<<1, 1024, 0, stream>>>(part, acc, out);
}